// Round 4
// baseline (3799.876 us; speedup 1.0000x reference)
//
#include <hip/hip_runtime.h>
#include <hip/hip_bf16.h>

// NeuralODE RK4, bf16 MFMA persistent kernel, swapped-operand layout.
// BS=1024, ZDIM=HID=256, TLEN=128 -> 127 steps x 4 stages = 508 f-evals.
//
// 64 WGs x 512 threads (8 waves, 2/SIMD). WG owns 16 batch rows; wave wv owns
// output cols [32wv, 32wv+32) for BOTH GEMMs. Weights in VGPRs, A-frag layout.
// (Role-split and 4-active-wave variants measured WORSE: phase-boundary TLP
// from 2 waves/SIMD is worth ~350 cyc/stage. LDS swizzle measured neutral-to-
// negative: original layout is already bank-throughput-optimal at full-wave
// granularity — 8 touches/bank per b128, 4/bank per b64, the minimum.)
//
// Swapped trick: S^T = W^T @ z^T (weights as MFMA A-operand). C/D layout:
// col(lane&15) = batch row m, row(q*4+r) = output col c. LDS round-trip is
// per-m contiguous: packed b64 writes, b128 frag reads, row stride 264 u16.
//
// This revision vs the 533us anchor:
//  - hsh[] table: no global t[] loads inside the step loop
//  - rotated k-slice order ks=(wv+i)&7: spreads the post-barrier LDS queue
//    across slices, reducing wave skew at the next barrier
//  - RK4 kacc bookkeeping deferred to after the barrier (overlaps next GEMM's
//    read latency); only zn pack+write stays on the pre-barrier critical path
//  - hbuf p0 written before p1's tanh is computed (shorter serial tail)

#define BS   1024
#define ZDIM 256
#define TLEN 128
#define ROWSTRIDE 264   // u16 units; 528 B = 16B-aligned, odd multiple of 4 units

typedef short v8s __attribute__((ext_vector_type(8)));
typedef float v4f __attribute__((ext_vector_type(4)));

static __device__ __forceinline__ ushort f2bf_rne(float x) {
    union { float f; unsigned u; } v; v.f = x;
    unsigned r = v.u + 0x7FFFu + ((v.u >> 16) & 1u);
    return (ushort)(r >> 16);
}

static __device__ __forceinline__ unsigned pk2(float a, float b) {
    union { __hip_bfloat162 h; unsigned u; } cv;
    cv.h = __float22bfloat162_rn(make_float2(a, b));
    return cv.u;
}

static __device__ __forceinline__ float fast_tanh(float x) {
    // tanh(x) = 1 - 2/(exp2(2x*log2e)+1); v_exp + v_rcp, no slow libm div
    float e = __builtin_amdgcn_exp2f(2.88539008177793f * x);
    float r = __builtin_amdgcn_rcpf(e + 1.0f);
    return 1.0f - 2.0f * r;
}

__global__ __launch_bounds__(512, 2)
void ode_mfma_kernel(const float* __restrict__ z0,
                     const float* __restrict__ t,
                     const float* __restrict__ W1,
                     const float* __restrict__ b1,
                     const float* __restrict__ W2,
                     const float* __restrict__ b2,
                     float* __restrict__ out)
{
    // state buffers, swapped layout: buf[m][c] bf16, row stride ROWSTRIDE
    __shared__ ushort zbuf[16 * ROWSTRIDE];
    __shared__ ushort hbuf[16 * ROWSTRIDE];
    __shared__ float  hsh[TLEN];            // per-step h = t[s+1]-t[s]

    const int tid  = threadIdx.x;
    const int wv   = tid >> 6;        // 0..7
    const int lane = tid & 63;
    const int q    = lane >> 4;       // 0..3
    const int ln   = lane & 15;       // = batch row m (within tile)
    const int rowbase = blockIdx.x * 16;

    if (tid < TLEN - 1) hsh[tid] = t[tid + 1] - t[tid];

    // ---- one-time: weights -> registers, A-frag layout ----
    // frag[ct][ks]: lane holds W[k = 32ks + 8q + j][c = 32wv + 16ct + ln]
    v8s w1f[2][8], w2f[2][8];
    #pragma unroll
    for (int ct = 0; ct < 2; ++ct) {
        const int c = wv * 32 + ct * 16 + ln;
        #pragma unroll
        for (int ks = 0; ks < 8; ++ks) {
            v8s a, b;
            #pragma unroll
            for (int j = 0; j < 8; ++j) {
                const int k = ks * 32 + q * 8 + j;
                a[j] = (short)f2bf_rne(W1[k * ZDIM + c]);
                b[j] = (short)f2bf_rne(W2[k * ZDIM + c]);
            }
            w1f[ct][ks] = a;
            w2f[ct][ks] = b;
        }
    }

    // biases in C'-layout: value row (c = 32wv + 16ct + 4q + r)
    v4f b1f[2], b2f[2];
    #pragma unroll
    for (int ct = 0; ct < 2; ++ct)
        #pragma unroll
        for (int r = 0; r < 4; ++r) {
            b1f[ct][r] = b1[wv * 32 + ct * 16 + q * 4 + r];
            b2f[ct][r] = b2[wv * 32 + ct * 16 + q * 4 + r];
        }

    // LDS offsets (u16 units); reads use rotated slice order ks=(wv+i)&7
    const int rdbase = ln * ROWSTRIDE + q * 8;            // + 32*ks, b128 reads
    const int wrbase = ln * ROWSTRIDE + wv * 32 + q * 4;  // + 16*ct,  b64 writes
    int rdaddr[8];
    #pragma unroll
    for (int i = 0; i < 8; ++i)
        rdaddr[i] = rdbase + ((wv + i) & 7) * 32;

    // ---- initial state ----
    float zloc[2][4];   // z[m=ln][c = 32wv+16ct+4q+r], fp32
    #pragma unroll
    for (int ct = 0; ct < 2; ++ct) {
        #pragma unroll
        for (int r = 0; r < 4; ++r)
            zloc[ct][r] = z0[(rowbase + ln) * ZDIM + wv * 32 + ct * 16 + q * 4 + r];
        uint2 p; p.x = pk2(zloc[ct][0], zloc[ct][1]); p.y = pk2(zloc[ct][2], zloc[ct][3]);
        *(uint2*)&zbuf[wrbase + ct * 16] = p;
    }
    __syncthreads();

    float kacc[2][4];

    #pragma unroll 1
    for (int step = 0; step < TLEN - 1; ++step) {
        const float h = hsh[step];

        #pragma unroll
        for (int stage = 0; stage < 4; ++stage) {
            // ---- GEMM1: S^T = W1^T z^T + b1 (rotated slice order) ----
            v4f acc0 = b1f[0], acc1 = b1f[1];
            #pragma unroll
            for (int i = 0; i < 8; ++i) {
                const int ks = (wv + i) & 7;
                const v8s zf = *(const v8s*)&zbuf[rdaddr[i]];
                acc0 = __builtin_amdgcn_mfma_f32_16x16x32_bf16(w1f[0][ks], zf, acc0, 0, 0, 0);
                acc1 = __builtin_amdgcn_mfma_f32_16x16x32_bf16(w1f[1][ks], zf, acc1, 0, 0, 0);
            }
            // tanh -> hbuf; write p0 before computing p1 (shorter tail)
            {
                uint2 p0;
                p0.x = pk2(fast_tanh(acc0[0]), fast_tanh(acc0[1]));
                p0.y = pk2(fast_tanh(acc0[2]), fast_tanh(acc0[3]));
                *(uint2*)&hbuf[wrbase] = p0;
                uint2 p1;
                p1.x = pk2(fast_tanh(acc1[0]), fast_tanh(acc1[1]));
                p1.y = pk2(fast_tanh(acc1[2]), fast_tanh(acc1[3]));
                *(uint2*)&hbuf[wrbase + 16] = p1;
            }
            __syncthreads();

            // ---- GEMM2: f^T = W2^T h^T + b2 (rotated slice order) ----
            v4f fv0 = b2f[0], fv1 = b2f[1];
            #pragma unroll
            for (int i = 0; i < 8; ++i) {
                const int ks = (wv + i) & 7;
                const v8s hf = *(const v8s*)&hbuf[rdaddr[i]];
                fv0 = __builtin_amdgcn_mfma_f32_16x16x32_bf16(w2f[0][ks], hf, fv0, 0, 0, 0);
                fv1 = __builtin_amdgcn_mfma_f32_16x16x32_bf16(w2f[1][ks], hf, fv1, 0, 0, 0);
            }

            // ---- RK4 epilogue: only zn pack+write before the barrier ----
            if (stage < 3) {
                const float c = (stage == 2) ? h : 0.5f * h;
                #pragma unroll
                for (int ct = 0; ct < 2; ++ct) {
                    const v4f f = ct ? fv1 : fv0;
                    float zn[4];
                    #pragma unroll
                    for (int r = 0; r < 4; ++r) zn[r] = zloc[ct][r] + c * f[r];
                    uint2 p; p.x = pk2(zn[0], zn[1]); p.y = pk2(zn[2], zn[3]);
                    *(uint2*)&zbuf[wrbase + ct * 16] = p;
                }
                __syncthreads();
                // deferred kacc bookkeeping: overlaps next GEMM1's reads
                #pragma unroll
                for (int ct = 0; ct < 2; ++ct) {
                    const v4f f = ct ? fv1 : fv0;
                    #pragma unroll
                    for (int r = 0; r < 4; ++r) {
                        if (stage == 0) kacc[ct][r] = f[r];
                        else            kacc[ct][r] += 2.0f * f[r];
                    }
                }
            } else {
                #pragma unroll
                for (int ct = 0; ct < 2; ++ct) {
                    const v4f f = ct ? fv1 : fv0;
                    #pragma unroll
                    for (int r = 0; r < 4; ++r) {
                        kacc[ct][r] += f[r];
                        zloc[ct][r] += (h * (1.0f / 6.0f)) * kacc[ct][r];
                    }
                    uint2 p; p.x = pk2(zloc[ct][0], zloc[ct][1]);
                    p.y = pk2(zloc[ct][2], zloc[ct][3]);
                    *(uint2*)&zbuf[wrbase + ct * 16] = p;
                }
                __syncthreads();
            }
        }
    }

    // ---- final store (one-time, uncoalesced is fine) ----
    #pragma unroll
    for (int ct = 0; ct < 2; ++ct)
        #pragma unroll
        for (int r = 0; r < 4; ++r)
            out[(rowbase + ln) * ZDIM + wv * 32 + ct * 16 + q * 4 + r] = zloc[ct][r];
}

extern "C" void kernel_launch(void* const* d_in, const int* in_sizes, int n_in,
                              void* d_out, int out_size, void* d_ws, size_t ws_size,
                              hipStream_t stream) {
    const float* z0 = (const float*)d_in[0];
    const float* t  = (const float*)d_in[1];
    const float* W1 = (const float*)d_in[2];
    const float* b1 = (const float*)d_in[3];
    const float* W2 = (const float*)d_in[4];
    const float* b2 = (const float*)d_in[5];
    float* out = (float*)d_out;

    dim3 grid(BS / 16);    // 64 workgroups, 16 batch rows each
    dim3 block(512);       // 8 waves, 2 per SIMD
    hipLaunchKernelGGL(ode_mfma_kernel, grid, block, 0, stream,
                       z0, t, W1, b1, W2, b2, out);
}

// Round 5
// 546.272 us; speedup vs baseline: 6.9560x; 6.9560x over previous
//
#include <hip/hip_runtime.h>
#include <hip/hip_bf16.h>

// NeuralODE RK4, bf16 MFMA persistent kernel, swapped-operand layout.
// BS=1024, ZDIM=HID=256, TLEN=128 -> 127 steps x 4 stages = 508 f-evals.
//
// 64 WGs x 512 threads (8 waves, 2/SIMD). WG owns 16 batch rows; wave wv owns
// output cols [32wv, 32wv+32) for BOTH GEMMs. Weights in VGPRs, A-frag layout.
//
// Swapped trick: S^T = W^T @ z^T (weights as MFMA A-operand). C/D layout:
// col(lane&15) = batch row m, row(q*4+r) = output col c. LDS round-trip is
// per-m contiguous: packed b64 writes, b128 frag reads, row stride 264 u16.
//
// Rotated k-slice order (spreads the post-barrier LDS queue): wave wv
// processes k-slices in order (wv+i)&7. CRITICAL: the weight fragments are
// stored PRE-ROTATED at load time (wf[ct][i] = slice (wv+i)&7) so every
// register-array index in the hot loop is compile-time static. R4 measured
// the runtime-indexed version: VGPR 112->52, 17 MB/dispatch scratch traffic,
// 6.6x slowdown (rule: runtime-indexed ext_vector arrays go to scratch).
//
// Other structure vs the 533us anchor:
//  - hsh[] table: no global t[] loads inside the step loop
//  - RK4 kacc bookkeeping deferred to after the barrier (overlaps next GEMM)
//  - hbuf p0 written before p1's tanh is computed (shorter serial tail)

#define BS   1024
#define ZDIM 256
#define TLEN 128
#define ROWSTRIDE 264   // u16 units; 528 B = 16B-aligned, odd multiple of 4 units

typedef short v8s __attribute__((ext_vector_type(8)));
typedef float v4f __attribute__((ext_vector_type(4)));

static __device__ __forceinline__ ushort f2bf_rne(float x) {
    union { float f; unsigned u; } v; v.f = x;
    unsigned r = v.u + 0x7FFFu + ((v.u >> 16) & 1u);
    return (ushort)(r >> 16);
}

static __device__ __forceinline__ unsigned pk2(float a, float b) {
    union { __hip_bfloat162 h; unsigned u; } cv;
    cv.h = __float22bfloat162_rn(make_float2(a, b));
    return cv.u;
}

static __device__ __forceinline__ float fast_tanh(float x) {
    // tanh(x) = 1 - 2/(exp2(2x*log2e)+1); v_exp + v_rcp, no slow libm div
    float e = __builtin_amdgcn_exp2f(2.88539008177793f * x);
    float r = __builtin_amdgcn_rcpf(e + 1.0f);
    return 1.0f - 2.0f * r;
}

__global__ __launch_bounds__(512, 2)
void ode_mfma_kernel(const float* __restrict__ z0,
                     const float* __restrict__ t,
                     const float* __restrict__ W1,
                     const float* __restrict__ b1,
                     const float* __restrict__ W2,
                     const float* __restrict__ b2,
                     float* __restrict__ out)
{
    // state buffers, swapped layout: buf[m][c] bf16, row stride ROWSTRIDE
    __shared__ ushort zbuf[16 * ROWSTRIDE];
    __shared__ ushort hbuf[16 * ROWSTRIDE];
    __shared__ float  hsh[TLEN];            // per-step h = t[s+1]-t[s]

    const int tid  = threadIdx.x;
    const int wv   = tid >> 6;        // 0..7
    const int lane = tid & 63;
    const int q    = lane >> 4;       // 0..3
    const int ln   = lane & 15;       // = batch row m (within tile)
    const int rowbase = blockIdx.x * 16;

    if (tid < TLEN - 1) hsh[tid] = t[tid + 1] - t[tid];

    // ---- one-time: weights -> registers, A-frag layout, PRE-ROTATED ----
    // wf[ct][i] holds k-slice ks=(wv+i)&7: lane has W[k=32ks+8q+j][c=32wv+16ct+ln]
    // (runtime ks only feeds the global-load address; register index i is static)
    v8s w1f[2][8], w2f[2][8];
    #pragma unroll
    for (int ct = 0; ct < 2; ++ct) {
        const int c = wv * 32 + ct * 16 + ln;
        #pragma unroll
        for (int i = 0; i < 8; ++i) {
            const int ks = (wv + i) & 7;
            v8s a, b;
            #pragma unroll
            for (int j = 0; j < 8; ++j) {
                const int k = ks * 32 + q * 8 + j;
                a[j] = (short)f2bf_rne(W1[k * ZDIM + c]);
                b[j] = (short)f2bf_rne(W2[k * ZDIM + c]);
            }
            w1f[ct][i] = a;
            w2f[ct][i] = b;
        }
    }

    // biases in C'-layout: value row (c = 32wv + 16ct + 4q + r)
    v4f b1f[2], b2f[2];
    #pragma unroll
    for (int ct = 0; ct < 2; ++ct)
        #pragma unroll
        for (int r = 0; r < 4; ++r) {
            b1f[ct][r] = b1[wv * 32 + ct * 16 + q * 4 + r];
            b2f[ct][r] = b2[wv * 32 + ct * 16 + q * 4 + r];
        }

    // LDS offsets (u16 units); rdaddr[i] carries the matching slice rotation
    const int rdbase = ln * ROWSTRIDE + q * 8;            // + 32*ks, b128 reads
    const int wrbase = ln * ROWSTRIDE + wv * 32 + q * 4;  // + 16*ct,  b64 writes
    int rdaddr[8];
    #pragma unroll
    for (int i = 0; i < 8; ++i)
        rdaddr[i] = rdbase + ((wv + i) & 7) * 32;

    // ---- initial state ----
    float zloc[2][4];   // z[m=ln][c = 32wv+16ct+4q+r], fp32
    #pragma unroll
    for (int ct = 0; ct < 2; ++ct) {
        #pragma unroll
        for (int r = 0; r < 4; ++r)
            zloc[ct][r] = z0[(rowbase + ln) * ZDIM + wv * 32 + ct * 16 + q * 4 + r];
        uint2 p; p.x = pk2(zloc[ct][0], zloc[ct][1]); p.y = pk2(zloc[ct][2], zloc[ct][3]);
        *(uint2*)&zbuf[wrbase + ct * 16] = p;
    }
    __syncthreads();

    float kacc[2][4];

    #pragma unroll 1
    for (int step = 0; step < TLEN - 1; ++step) {
        const float h = hsh[step];

        #pragma unroll
        for (int stage = 0; stage < 4; ++stage) {
            // ---- GEMM1: S^T = W1^T z^T + b1 (rotated slice order) ----
            v4f acc0 = b1f[0], acc1 = b1f[1];
            #pragma unroll
            for (int i = 0; i < 8; ++i) {
                const v8s zf = *(const v8s*)&zbuf[rdaddr[i]];
                acc0 = __builtin_amdgcn_mfma_f32_16x16x32_bf16(w1f[0][i], zf, acc0, 0, 0, 0);
                acc1 = __builtin_amdgcn_mfma_f32_16x16x32_bf16(w1f[1][i], zf, acc1, 0, 0, 0);
            }
            // tanh -> hbuf; write p0 before computing p1 (shorter tail)
            {
                uint2 p0;
                p0.x = pk2(fast_tanh(acc0[0]), fast_tanh(acc0[1]));
                p0.y = pk2(fast_tanh(acc0[2]), fast_tanh(acc0[3]));
                *(uint2*)&hbuf[wrbase] = p0;
                uint2 p1;
                p1.x = pk2(fast_tanh(acc1[0]), fast_tanh(acc1[1]));
                p1.y = pk2(fast_tanh(acc1[2]), fast_tanh(acc1[3]));
                *(uint2*)&hbuf[wrbase + 16] = p1;
            }
            __syncthreads();

            // ---- GEMM2: f^T = W2^T h^T + b2 (rotated slice order) ----
            v4f fv0 = b2f[0], fv1 = b2f[1];
            #pragma unroll
            for (int i = 0; i < 8; ++i) {
                const v8s hf = *(const v8s*)&hbuf[rdaddr[i]];
                fv0 = __builtin_amdgcn_mfma_f32_16x16x32_bf16(w2f[0][i], hf, fv0, 0, 0, 0);
                fv1 = __builtin_amdgcn_mfma_f32_16x16x32_bf16(w2f[1][i], hf, fv1, 0, 0, 0);
            }

            // ---- RK4 epilogue: only zn pack+write before the barrier ----
            if (stage < 3) {
                const float c = (stage == 2) ? h : 0.5f * h;
                #pragma unroll
                for (int ct = 0; ct < 2; ++ct) {
                    const v4f f = ct ? fv1 : fv0;
                    float zn[4];
                    #pragma unroll
                    for (int r = 0; r < 4; ++r) zn[r] = zloc[ct][r] + c * f[r];
                    uint2 p; p.x = pk2(zn[0], zn[1]); p.y = pk2(zn[2], zn[3]);
                    *(uint2*)&zbuf[wrbase + ct * 16] = p;
                }
                __syncthreads();
                // deferred kacc bookkeeping: overlaps next GEMM1's reads
                #pragma unroll
                for (int ct = 0; ct < 2; ++ct) {
                    const v4f f = ct ? fv1 : fv0;
                    #pragma unroll
                    for (int r = 0; r < 4; ++r) {
                        if (stage == 0) kacc[ct][r] = f[r];
                        else            kacc[ct][r] += 2.0f * f[r];
                    }
                }
            } else {
                #pragma unroll
                for (int ct = 0; ct < 2; ++ct) {
                    const v4f f = ct ? fv1 : fv0;
                    #pragma unroll
                    for (int r = 0; r < 4; ++r) {
                        kacc[ct][r] += f[r];
                        zloc[ct][r] += (h * (1.0f / 6.0f)) * kacc[ct][r];
                    }
                    uint2 p; p.x = pk2(zloc[ct][0], zloc[ct][1]);
                    p.y = pk2(zloc[ct][2], zloc[ct][3]);
                    *(uint2*)&zbuf[wrbase + ct * 16] = p;
                }
                __syncthreads();
            }
        }
    }

    // ---- final store (one-time, uncoalesced is fine) ----
    #pragma unroll
    for (int ct = 0; ct < 2; ++ct)
        #pragma unroll
        for (int r = 0; r < 4; ++r)
            out[(rowbase + ln) * ZDIM + wv * 32 + ct * 16 + q * 4 + r] = zloc[ct][r];
}

extern "C" void kernel_launch(void* const* d_in, const int* in_sizes, int n_in,
                              void* d_out, int out_size, void* d_ws, size_t ws_size,
                              hipStream_t stream) {
    const float* z0 = (const float*)d_in[0];
    const float* t  = (const float*)d_in[1];
    const float* W1 = (const float*)d_in[2];
    const float* b1 = (const float*)d_in[3];
    const float* W2 = (const float*)d_in[4];
    const float* b2 = (const float*)d_in[5];
    float* out = (float*)d_out;

    dim3 grid(BS / 16);    // 64 workgroups, 16 batch rows each
    dim3 block(512);       // 8 waves, 2 per SIMD
    hipLaunchKernelGGL(ode_mfma_kernel, grid, block, 0, stream,
                       z0, t, W1, b1, W2, b2, out);
}